// Round 4
// baseline (140.809 us; speedup 1.0000x reference)
//
#include <hip/hip_runtime.h>

#define N_NODES 50000
#define N_EDGES 500000
#define D 128
#define CAP 64                                   // slots per node; max-deg ~30
#define NCHUNK 256                               // edge chunks (one block each)
#define EPC ((N_EDGES + NCHUNK - 1) / NCHUNK)    // 1954 edges per chunk
#define NWORDS ((N_NODES + 3) / 4)               // 12500 u32 words of packed u8 counters

typedef unsigned long long u64;

// ---- P1: per-chunk dst histogram in LDS (byte-packed counters, no global atomics).
// Extra block (blockIdx.x == NCHUNK) computes v = W1@(W2@Wf), c1, c0 overlapped.
__global__ void hist_kernel(const int* __restrict__ dst,
                            const float* __restrict__ W1, const float* __restrict__ W2,
                            const float* __restrict__ b1, const float* __restrict__ b2,
                            const float* __restrict__ Wf, const float* __restrict__ bf,
                            unsigned* __restrict__ hist32, float* __restrict__ v,
                            float* __restrict__ consts) {
    if ((int)blockIdx.x == NCHUNK) {
        __shared__ float u[D];
        int t = threadIdx.x;
        if (t < D) {
            float a = 0.f;
#pragma unroll 8
            for (int j = 0; j < D; ++j) a += W2[t * D + j] * Wf[j];
            u[t] = a;
        }
        __syncthreads();
        if (t < D) {
            float a = 0.f;
#pragma unroll 8
            for (int k = 0; k < D; ++k) a += W1[t * D + k] * u[k];
            v[t] = a;
        }
        if (t == 0) {
            float c = 0.f;
            for (int k = 0; k < D; ++k) c += b1[k] * u[k];
            consts[0] = c;
        } else if (t == 1) {
            float c = bf[0];
            for (int k = 0; k < D; ++k) c += b2[k] * Wf[k];
            consts[1] = c;
        }
        return;
    }
    __shared__ unsigned lds[NWORDS];             // 50 KB packed u8 counters
    const int t = threadIdx.x;
    const int c = blockIdx.x;
    for (int i = t; i < NWORDS; i += 256) lds[i] = 0u;
    __syncthreads();
    const int e0 = c * EPC;
    const int e1 = (e0 + EPC < N_EDGES) ? e0 + EPC : N_EDGES;
    for (int e = e0 + t; e < e1; e += 256) {
        int d = dst[e];
        atomicAdd(&lds[d >> 2], 1u << (8 * (d & 3)));   // per-chunk count <= 30: no carry-out
    }
    __syncthreads();
    unsigned* outw = hist32 + (size_t)c * NWORDS;
    for (int i = t; i < NWORDS; i += 256) outw[i] = lds[i];
}

// ---- P2: per-node exclusive prefix over the 256 chunk counts -> u8 base offsets + cnt.
__global__ void scan_kernel(const unsigned char* __restrict__ hist8,
                            unsigned char* __restrict__ base8, int* __restrict__ cntv) {
    int n = blockIdx.x * blockDim.x + threadIdx.x;
    if (n >= N_NODES) return;
    int run = 0;
#pragma unroll 8
    for (int c = 0; c < NCHUNK; ++c) {
        int b = hist8[(size_t)c * (NWORDS * 4) + n];   // coalesced across threads
        base8[(size_t)c * (NWORDS * 4) + n] = (unsigned char)run;
        run += b;
    }
    cntv[n] = (run < CAP) ? run : CAP;
}

// ---- P3: placement. Block = chunk: load its base row into LDS (packed u8 in u32),
// slot = base + intra-chunk rank via returning LDS atomic, write (src, w) bin entry.
__global__ void place_kernel(const int* __restrict__ src, const int* __restrict__ dst,
                             const float* __restrict__ ew,
                             const unsigned* __restrict__ base32, int2* __restrict__ pairs) {
    __shared__ unsigned lds[NWORDS];
    const int t = threadIdx.x;
    const int c = blockIdx.x;
    const unsigned* inw = base32 + (size_t)c * NWORDS;
    for (int i = t; i < NWORDS; i += 256) lds[i] = inw[i];
    __syncthreads();
    const int e0 = c * EPC;
    const int e1 = (e0 + EPC < N_EDGES) ? e0 + EPC : N_EDGES;
    for (int e = e0 + t; e < e1; e += 256) {
        int d = dst[e];
        int sh = 8 * (d & 3);
        unsigned old = atomicAdd(&lds[d >> 2], 1u << sh);
        int slot = (int)((old >> sh) & 0xffu);
        if (slot < CAP)   // safety clamp; never taken for this graph
            pairs[(size_t)d * CAP + slot] = make_int2(src[e], __float_as_int(ew[e]));
    }
}

// ---- gemv: 32 lanes/node, float4 loads; t[n] = x[n,:].v ; epilogue sums the node's
// own bin weights in fp32 -> deg -> dinv[n], tw[n] = dinv[n]*t[n].
__global__ void gemv_kernel(const float* __restrict__ x, const float* __restrict__ v,
                            const int2* __restrict__ pairs, const int* __restrict__ cntv,
                            float* __restrict__ dinv, float* __restrict__ tw) {
    __shared__ float vs[D];
    const int t = threadIdx.x;
    if (t < D) vs[t] = v[t];
    __syncthreads();
    const int l = t & 31;
    const int n = blockIdx.x * 8 + (t >> 5);   // 50000 = 6250*8, exact
    float4 xv = ((const float4*)(x + (size_t)n * D))[l];
    float a = xv.x * vs[l * 4] + xv.y * vs[l * 4 + 1] +
              xv.z * vs[l * 4 + 2] + xv.w * vs[l * 4 + 3];
    // weighted degree from own bin (contiguous 32x int2 = 256B per wave-group)
    int cnt = cntv[n];
    const int2* row = pairs + (size_t)n * CAP;
    float wsum = 0.f;
    for (int i = l; i < cnt; i += 32) wsum += __int_as_float(row[i].y);
#pragma unroll
    for (int off = 16; off > 0; off >>= 1) {
        a    += __shfl_xor(a, off);
        wsum += __shfl_xor(wsum, off);
    }
    if (l == 0) {
        float di = rsqrtf(wsum + 1.0f);
        dinv[n] = di;
        tw[n] = di * a;
    }
}

// ---- s-pass: 4 lanes/node, int4 bin reads (2 pairs/load):
// sw[n] = dinv[n] * ( dinv[n]*(sum ew*tw[src] + tw[n]) + c1 )
__global__ void gather_s_kernel(const float* __restrict__ tw, const float* __restrict__ dinv,
                                const int* __restrict__ cntv, const int2* __restrict__ pairs,
                                const float* __restrict__ consts, float* __restrict__ sw) {
    int tid = threadIdx.x;
    int n = blockIdx.x * 64 + (tid >> 2);
    int l = tid & 3;
    if (n >= N_NODES) return;
    int cnt = cntv[n];
    const int4* row = (const int4*)(pairs + (size_t)n * CAP);
    float acc = 0.f;
    for (int c = l; 2 * c < cnt; c += 4) {
        int4 p = row[c];
        acc += __int_as_float(p.y) * tw[p.x];
        if (2 * c + 1 < cnt) acc += __int_as_float(p.w) * tw[p.z];
    }
    acc += __shfl_xor(acc, 1);
    acc += __shfl_xor(acc, 2);
    if (l == 0) {
        float di = dinv[n];
        float s = di * (acc + tw[n]) + consts[0];
        sw[n] = di * s;
    }
}

// ---- z-pass: out[n] = sigmoid( dinv[n]*(sum ew*sw[src] + sw[n]) + c0 ) * 10
__global__ void gather_z_kernel(const float* __restrict__ sw, const float* __restrict__ dinv,
                                const int* __restrict__ cntv, const int2* __restrict__ pairs,
                                const float* __restrict__ consts, float* __restrict__ out) {
    int tid = threadIdx.x;
    int n = blockIdx.x * 64 + (tid >> 2);
    int l = tid & 3;
    if (n >= N_NODES) return;
    int cnt = cntv[n];
    const int4* row = (const int4*)(pairs + (size_t)n * CAP);
    float acc = 0.f;
    for (int c = l; 2 * c < cnt; c += 4) {
        int4 p = row[c];
        acc += __int_as_float(p.y) * sw[p.x];
        if (2 * c + 1 < cnt) acc += __int_as_float(p.w) * sw[p.z];
    }
    acc += __shfl_xor(acc, 1);
    acc += __shfl_xor(acc, 2);
    if (l == 0) {
        float di = dinv[n];
        float z = di * (acc + sw[n]) + consts[1];
        out[n] = 10.0f / (1.0f + expf(-z));
    }
}

extern "C" void kernel_launch(void* const* d_in, const int* in_sizes, int n_in,
                              void* d_out, int out_size, void* d_ws, size_t ws_size,
                              hipStream_t stream) {
    const float* x  = (const float*)d_in[0];
    const int*   ei = (const int*)d_in[1];
    const float* ew = (const float*)d_in[2];
    const float* W1 = (const float*)d_in[3];
    const float* b1 = (const float*)d_in[4];
    const float* W2 = (const float*)d_in[5];
    const float* b2 = (const float*)d_in[6];
    const float* Wf = (const float*)d_in[7];
    const float* bf = (const float*)d_in[8];
    const int* srcv = ei;
    const int* dstv = ei + N_EDGES;
    float* out = (float*)d_out;

    char* p = (char*)d_ws;
    auto alloc = [&](size_t bytes) { void* r = (void*)p; p += (bytes + 255) & ~(size_t)255; return r; };
    unsigned*      hist32 = (unsigned*)alloc((size_t)NCHUNK * NWORDS * 4);   // 12.8 MB
    unsigned char* base8  = (unsigned char*)alloc((size_t)NCHUNK * NWORDS * 4); // 12.8 MB
    int*   cntv   = (int*)alloc(N_NODES * 4);
    float* dinv   = (float*)alloc(N_NODES * 4);
    float* tw     = (float*)alloc(N_NODES * 4);
    float* sw     = (float*)alloc(N_NODES * 4);
    float* v      = (float*)alloc(D * 4);
    float* consts = (float*)alloc(2 * 4);
    int2*  pairs  = (int2*)alloc((size_t)N_NODES * CAP * 8);   // 25.6 MB

    const int GB = (N_NODES + 63) / 64;   // 782 blocks, 64 nodes each
    const int NB = (N_NODES + 255) / 256; // 196

    // P1: per-chunk LDS histograms (+ weight collapse in the extra block). No memset needed.
    hist_kernel<<<NCHUNK + 1, 256, 0, stream>>>(dstv, W1, W2, b1, b2, Wf, bf,
                                                hist32, v, consts);

    // P2: per-node prefix over chunks -> base offsets + cnt
    scan_kernel<<<NB, 256, 0, stream>>>((const unsigned char*)hist32, base8, cntv);

    // P3: placement via returning LDS atomics (no global atomics anywhere)
    place_kernel<<<NCHUNK, 256, 0, stream>>>(srcv, dstv, ew,
                                             (const unsigned*)base8, pairs);

    // t = x@v ; deg from own bin -> dinv, tw = dinv*t
    gemv_kernel<<<N_NODES / 8, 256, 0, stream>>>(x, v, pairs, cntv, dinv, tw);

    // two gather rounds (4 lanes/node, int4 bin reads)
    gather_s_kernel<<<GB, 256, 0, stream>>>(tw, dinv, cntv, pairs, consts, sw);
    gather_z_kernel<<<GB, 256, 0, stream>>>(sw, dinv, cntv, pairs, consts, out);
}

// Round 6
// 138.971 us; speedup vs baseline: 1.0132x; 1.0132x over previous
//
#include <hip/hip_runtime.h>

#define N_NODES 50000
#define N_EDGES 500000
#define D 128
#define FXS 4194304.0f   // 2^22 fixed-point scale for weighted degree (deterministic)
#define CAP 64           // slots per node; deg ~ Poisson(10), max-deg ~30
#define DPAD 8           // degcnt stride in u64: one node per 64B line (contention exp.)
#define EBLK 489         // ceil(125000 / 256): 4-edge/thread pass1 blocks
#define GEMVB 2048       // gemv blocks (grid-stride over 6250 groups of 8 nodes)

typedef unsigned long long u64;

// ---- prep: block 0 collapses weights (v, c1, c0); blocks 1.. zero padded degcnt.
// Replaces the hipMemsetAsync dispatch.
__global__ void prep_kernel(const float* __restrict__ W1, const float* __restrict__ W2,
                            const float* __restrict__ b1, const float* __restrict__ b2,
                            const float* __restrict__ Wf, const float* __restrict__ bf,
                            float* __restrict__ v, float* __restrict__ consts,
                            u64* __restrict__ degcnt) {
    const int t = threadIdx.x;
    if (blockIdx.x == 0) {
        __shared__ float u[D];
        if (t < D) {
            float a = 0.f;
#pragma unroll 8
            for (int j = 0; j < D; ++j) a += W2[t * D + j] * Wf[j];
            u[t] = a;                         // u = W2 @ Wf
        }
        __syncthreads();
        if (t < D) {
            float a = 0.f;
#pragma unroll 8
            for (int k = 0; k < D; ++k) a += W1[t * D + k] * u[k];
            v[t] = a;                         // v = W1 @ u
        }
        if (t == 0) {
            float c = 0.f;
            for (int k = 0; k < D; ++k) c += b1[k] * u[k];
            consts[0] = c;                    // c1 = b1 . u
        } else if (t == 1) {
            float c = bf[0];
            for (int k = 0; k < D; ++k) c += b2[k] * Wf[k];
            consts[1] = c;                    // c0 = b2 . Wf + bf
        }
        return;
    }
    // zero 50000*DPAD u64 (3.2 MB)
    for (int i = (blockIdx.x - 1) * 256 + t; i < N_NODES * DPAD; i += 255 * 256)
        degcnt[i] = 0ull;
}

// ---- work: block-specialized fused dispatch.
// blocks [0, EBLK): 4-edge/thread returning-atomic slot assignment + bin fill
//                   (atomic-latency pipe, near-zero BW)
// blocks [EBLK, EBLK+GEMVB): raw gemv t[n] = x[n,:].v  (BW pipe, 25.6 MB stream)
// Independent: they co-schedule across CUs; epilogue kernel joins them.
__global__ void work_kernel(const int* __restrict__ src, const int* __restrict__ dst,
                            const float* __restrict__ ew, const float* __restrict__ x,
                            const float* __restrict__ v,
                            u64* __restrict__ degcnt, int2* __restrict__ pairs,
                            float* __restrict__ traw) {
    const int t = threadIdx.x;
    const int bid = blockIdx.x;
    if (bid < EBLK) {
        int q = bid * 256 + t;
        if (q < N_EDGES / 4) {               // 125000 quads
            int4   d4 = ((const int4*)dst)[q];
            int4   s4 = ((const int4*)src)[q];
            float4 w4 = ((const float4*)ew)[q];
            unsigned f0 = __float2uint_rn(w4.x * FXS);
            unsigned f1 = __float2uint_rn(w4.y * FXS);
            unsigned f2 = __float2uint_rn(w4.z * FXS);
            unsigned f3 = __float2uint_rn(w4.w * FXS);
            // 4 independent returning atomics; one node per 64B line (DPAD)
            u64 o0 = atomicAdd(&degcnt[(size_t)d4.x * DPAD], (1ull << 32) | (u64)f0);
            u64 o1 = atomicAdd(&degcnt[(size_t)d4.y * DPAD], (1ull << 32) | (u64)f1);
            u64 o2 = atomicAdd(&degcnt[(size_t)d4.z * DPAD], (1ull << 32) | (u64)f2);
            u64 o3 = atomicAdd(&degcnt[(size_t)d4.w * DPAD], (1ull << 32) | (u64)f3);
            int s0 = (int)(o0 >> 32), s1 = (int)(o1 >> 32);
            int s2 = (int)(o2 >> 32), s3 = (int)(o3 >> 32);
            if (s0 < CAP) pairs[(size_t)d4.x * CAP + s0] = make_int2(s4.x, __float_as_int(w4.x));
            if (s1 < CAP) pairs[(size_t)d4.y * CAP + s1] = make_int2(s4.y, __float_as_int(w4.y));
            if (s2 < CAP) pairs[(size_t)d4.z * CAP + s2] = make_int2(s4.z, __float_as_int(w4.z));
            if (s3 < CAP) pairs[(size_t)d4.w * CAP + s3] = make_int2(s4.w, __float_as_int(w4.w));
        }
        return;
    }
    // gemv portion
    __shared__ float vs[D];
    if (t < D) vs[t] = v[t];
    __syncthreads();
    const int l = t & 31;
    const int sub = t >> 5;
    for (int g = bid - EBLK; g < N_NODES / 8; g += GEMVB) {   // 6250 groups
        int n = g * 8 + sub;
        float4 xv = ((const float4*)(x + (size_t)n * D))[l];
        float a = xv.x * vs[l * 4] + xv.y * vs[l * 4 + 1] +
                  xv.z * vs[l * 4 + 2] + xv.w * vs[l * 4 + 3];
#pragma unroll
        for (int off = 16; off > 0; off >>= 1) a += __shfl_xor(a, off);
        if (l == 0) traw[n] = a;             // raw dot; scaled in epilogue
    }
}

// ---- epilogue: dinv[n], cnt[n], tw[n] = dinv*traw
__global__ void epi_kernel(const u64* __restrict__ degcnt, const float* __restrict__ traw,
                           float* __restrict__ dinv, int* __restrict__ cntv,
                           float* __restrict__ tw) {
    int n = blockIdx.x * blockDim.x + threadIdx.x;
    if (n < N_NODES) {
        u64 dc = degcnt[(size_t)n * DPAD];
        int c = (int)(dc >> 32);
        float deg = (float)(unsigned)(dc & 0xffffffffu) * (1.0f / FXS);
        float di = rsqrtf(deg + 1.0f);
        dinv[n] = di;
        cntv[n] = (c < CAP) ? c : CAP;
        tw[n] = di * traw[n];
    }
}

// ---- s-pass: 4 lanes/node, int4 bin reads (2 pairs/load):
// sw[n] = dinv[n] * ( dinv[n]*(sum ew*tw[src] + tw[n]) + c1 )
__global__ void gather_s_kernel(const float* __restrict__ tw, const float* __restrict__ dinv,
                                const int* __restrict__ cntv, const int2* __restrict__ pairs,
                                const float* __restrict__ consts, float* __restrict__ sw) {
    int tid = threadIdx.x;
    int n = blockIdx.x * 64 + (tid >> 2);
    int l = tid & 3;
    if (n >= N_NODES) return;
    int cnt = cntv[n];
    const int4* row = (const int4*)(pairs + (size_t)n * CAP);
    float acc = 0.f;
    for (int c = l; 2 * c < cnt; c += 4) {
        int4 p = row[c];
        acc += __int_as_float(p.y) * tw[p.x];
        if (2 * c + 1 < cnt) acc += __int_as_float(p.w) * tw[p.z];
    }
    acc += __shfl_xor(acc, 1);
    acc += __shfl_xor(acc, 2);
    if (l == 0) {
        float di = dinv[n];
        float s = di * (acc + tw[n]) + consts[0];
        sw[n] = di * s;
    }
}

// ---- z-pass: out[n] = sigmoid( dinv[n]*(sum ew*sw[src] + sw[n]) + c0 ) * 10
__global__ void gather_z_kernel(const float* __restrict__ sw, const float* __restrict__ dinv,
                                const int* __restrict__ cntv, const int2* __restrict__ pairs,
                                const float* __restrict__ consts, float* __restrict__ out) {
    int tid = threadIdx.x;
    int n = blockIdx.x * 64 + (tid >> 2);
    int l = tid & 3;
    if (n >= N_NODES) return;
    int cnt = cntv[n];
    const int4* row = (const int4*)(pairs + (size_t)n * CAP);
    float acc = 0.f;
    for (int c = l; 2 * c < cnt; c += 4) {
        int4 p = row[c];
        acc += __int_as_float(p.y) * sw[p.x];
        if (2 * c + 1 < cnt) acc += __int_as_float(p.w) * sw[p.z];
    }
    acc += __shfl_xor(acc, 1);
    acc += __shfl_xor(acc, 2);
    if (l == 0) {
        float di = dinv[n];
        float z = di * (acc + sw[n]) + consts[1];
        out[n] = 10.0f / (1.0f + expf(-z));
    }
}

extern "C" void kernel_launch(void* const* d_in, const int* in_sizes, int n_in,
                              void* d_out, int out_size, void* d_ws, size_t ws_size,
                              hipStream_t stream) {
    const float* x  = (const float*)d_in[0];
    const int*   ei = (const int*)d_in[1];
    const float* ew = (const float*)d_in[2];
    const float* W1 = (const float*)d_in[3];
    const float* b1 = (const float*)d_in[4];
    const float* W2 = (const float*)d_in[5];
    const float* b2 = (const float*)d_in[6];
    const float* Wf = (const float*)d_in[7];
    const float* bf = (const float*)d_in[8];
    const int* srcv = ei;
    const int* dstv = ei + N_EDGES;
    float* out = (float*)d_out;

    char* p = (char*)d_ws;
    auto alloc = [&](size_t bytes) { void* r = (void*)p; p += (bytes + 255) & ~(size_t)255; return r; };
    u64*   degcnt = (u64*)alloc((size_t)N_NODES * DPAD * 8);   // 3.2 MB padded
    float* dinv   = (float*)alloc(N_NODES * 4);
    int*   cntv   = (int*)alloc(N_NODES * 4);
    float* traw   = (float*)alloc(N_NODES * 4);
    float* tw     = (float*)alloc(N_NODES * 4);
    float* sw     = (float*)alloc(N_NODES * 4);
    float* v      = (float*)alloc(D * 4);
    float* consts = (float*)alloc(2 * 4);
    int2*  pairs  = (int2*)alloc((size_t)N_NODES * CAP * 8);   // 25.6 MB

    const int GB = (N_NODES + 63) / 64;    // 782
    const int NB = (N_NODES + 255) / 256;  // 196

    // prep: weight collapse + zero padded degcnt (no hipMemsetAsync)
    prep_kernel<<<256, 256, 0, stream>>>(W1, W2, b1, b2, Wf, bf, v, consts, degcnt);

    // fused: pass1 bin fill (atomic pipe) || gemv (BW pipe)
    work_kernel<<<EBLK + GEMVB, 256, 0, stream>>>(srcv, dstv, ew, x, v,
                                                  degcnt, pairs, traw);

    // join: dinv/cnt/tw
    epi_kernel<<<NB, 256, 0, stream>>>(degcnt, traw, dinv, cntv, tw);

    // two gather rounds
    gather_s_kernel<<<GB, 256, 0, stream>>>(tw, dinv, cntv, pairs, consts, sw);
    gather_z_kernel<<<GB, 256, 0, stream>>>(sw, dinv, cntv, pairs, consts, out);
}